// Round 1
// baseline (217.780 us; speedup 1.0000x reference)
//
#include <hip/hip_runtime.h>
#include <hip/hip_bf16.h>
#include <stdint.h>

typedef __attribute__((ext_vector_type(8))) short short8;
typedef __attribute__((ext_vector_type(4))) float floatx4;
typedef __attribute__((ext_vector_type(4))) unsigned int uintx4;

#define HH 64
#define WW 64
#define HWSZ 4096
#define BB 8
#define CIN 256
#define COUT 256
#define NTOT 32768  // B*H*W

__device__ __forceinline__ unsigned short f2b(float f) {
    union { float f; unsigned int u; } v; v.f = f;
    unsigned int r = v.u + 0x7FFFu + ((v.u >> 16) & 1u);
    return (unsigned short)(r >> 16);
}
__device__ __forceinline__ float b2f(unsigned short h) {
    union { unsigned int u; float f; } v; v.u = ((unsigned int)h) << 16;
    return v.f;
}

// ---- transpose + cast: [B][Cin][HW] f32 -> [B*HW][Cin] bf16 ----
__global__ void transpose_cast(const float* __restrict__ y, const float* __restrict__ x,
                               unsigned short* __restrict__ yT, unsigned short* __restrict__ xT) {
    __shared__ float tile[32][33];
    int z = blockIdx.z;          // 0..15: (b, which)
    int which = z & 1;           // 0 -> y, 1 -> x
    int b = z >> 1;
    const float* src = which ? x : y;
    unsigned short* dst = which ? xT : yT;
    int p0 = blockIdx.x * 32;    // pixel tile
    int i0 = blockIdx.y * 32;    // channel tile
    int t = threadIdx.x;
    int p = t & 31;
    int ib = t >> 5;             // 0..7
    const float* sp = src + (size_t)b * CIN * HWSZ + (size_t)i0 * HWSZ + p0;
    for (int r = 0; r < 4; ++r) {
        int i = ib + r * 8;
        tile[i][p] = sp[(size_t)i * HWSZ + p];
    }
    __syncthreads();
    int ii = t & 31;
    int pb = t >> 5;
    unsigned short* dp = dst + ((size_t)b * HWSZ + p0) * CIN + i0;
    for (int r = 0; r < 4; ++r) {
        int pp = pb + r * 8;
        dp[(size_t)pp * CIN + ii] = f2b(tile[ii][pp]);
    }
}

// ---- weight cast: 3x [256][256] f32 -> bf16 (layout unchanged, [m][k]) ----
__global__ void wcast(const float* __restrict__ wq, const float* __restrict__ wk,
                      const float* __restrict__ wv,
                      unsigned short* __restrict__ wqb, unsigned short* __restrict__ wkb,
                      unsigned short* __restrict__ wvb) {
    int idx = blockIdx.x * 256 + threadIdx.x;   // < 65536
    wqb[idx] = f2b(wq[idx]);
    wkb[idx] = f2b(wk[idx]);
    wvb[idx] = f2b(wv[idx]);
}

// ---- GEMM: Out[m][n] = sum_k W[m][k] * InT[n][k], bf16 MFMA 16x16x32 ----
// blockIdx.z selects (W, In, Out) among q/k/v.
#define BM 128
#define BN 128
#define BK 32
#define LDSS 40   // bf16 elems per LDS row (32 + 8 pad) = 80 B, 16B-aligned rows

__global__ __launch_bounds__(256, 4)
void gemm_qkv(const unsigned short* __restrict__ wqb, const unsigned short* __restrict__ wkb,
              const unsigned short* __restrict__ wvb,
              const unsigned short* __restrict__ yT, const unsigned short* __restrict__ xT,
              unsigned short* __restrict__ Qb, unsigned short* __restrict__ Kb,
              unsigned short* __restrict__ Vb) {
    __shared__ unsigned short lA[BM * LDSS];
    __shared__ unsigned short lB[BN * LDSS];

    int z = blockIdx.z;
    const unsigned short* Wb = (z == 0) ? wqb : (z == 1) ? wkb : wvb;
    const unsigned short* In = (z == 0) ? yT : xT;
    unsigned short* Out = (z == 0) ? Qb : (z == 1) ? Kb : Vb;

    int n0 = blockIdx.x * BN;
    int m0 = blockIdx.y * BM;
    int t = threadIdx.x;
    int lane = t & 63;
    int wave = t >> 6;
    int quad = lane >> 4;
    int l16 = lane & 15;
    int wm = (wave >> 1) * 64;
    int wn = (wave & 1) * 64;

    floatx4 acc[4][4];
    for (int mi = 0; mi < 4; ++mi)
        for (int ni = 0; ni < 4; ++ni)
            acc[mi][ni] = (floatx4){0.f, 0.f, 0.f, 0.f};

    int r0 = t >> 2, cch0 = t & 3;          // chunk t
    int r1 = (t + 256) >> 2;                // chunk t+256 (same cch)

    for (int k0 = 0; k0 < CIN; k0 += BK) {
        uintx4 a0 = *(const uintx4*)(Wb + (size_t)(m0 + r0) * CIN + k0 + cch0 * 8);
        uintx4 a1 = *(const uintx4*)(Wb + (size_t)(m0 + r1) * CIN + k0 + cch0 * 8);
        uintx4 b0 = *(const uintx4*)(In + (size_t)(n0 + r0) * CIN + k0 + cch0 * 8);
        uintx4 b1 = *(const uintx4*)(In + (size_t)(n0 + r1) * CIN + k0 + cch0 * 8);
        *(uintx4*)(lA + r0 * LDSS + cch0 * 8) = a0;
        *(uintx4*)(lA + r1 * LDSS + cch0 * 8) = a1;
        *(uintx4*)(lB + r0 * LDSS + cch0 * 8) = b0;
        *(uintx4*)(lB + r1 * LDSS + cch0 * 8) = b1;
        __syncthreads();

        short8 af[4], bf[4];
        for (int mi = 0; mi < 4; ++mi)
            af[mi] = *(const short8*)(lA + (wm + mi * 16 + l16) * LDSS + quad * 8);
        for (int ni = 0; ni < 4; ++ni)
            bf[ni] = *(const short8*)(lB + (wn + ni * 16 + l16) * LDSS + quad * 8);
        for (int mi = 0; mi < 4; ++mi)
            for (int ni = 0; ni < 4; ++ni)
                acc[mi][ni] = __builtin_amdgcn_mfma_f32_16x16x32_bf16(af[mi], bf[ni], acc[mi][ni], 0, 0, 0);
        __syncthreads();
    }

    // epilogue: C/D layout col = lane&15, row = quad*4 + reg
    for (int mi = 0; mi < 4; ++mi) {
        for (int ni = 0; ni < 4; ++ni) {
            int col = n0 + wn + ni * 16 + l16;
            int rowb = m0 + wm + mi * 16 + quad * 4;
            for (int r = 0; r < 4; ++r)
                Out[(size_t)(rowb + r) * NTOT + col] = f2b(acc[mi][ni][r]);
        }
    }
}

// ---- attention: per (b,c,h,w) 3x3 window softmax ----
__global__ void attn(const unsigned short* __restrict__ Q,
                     const unsigned short* __restrict__ K,
                     const unsigned short* __restrict__ V,
                     const float* __restrict__ rel_h,
                     const float* __restrict__ rel_w,
                     float* __restrict__ out) {
    int gid = blockIdx.x * 256 + threadIdx.x;
    int w = gid & 63;
    int h = (gid >> 6) & 63;
    int c = (gid >> 12) & 255;
    int b = gid >> 20;
    size_t nbase = (size_t)c * NTOT + (size_t)b * HWSZ;
    float q = b2f(Q[nbase + h * 64 + w]);
    bool use_h = (c < 128);
    float rel[3];
    if (use_h) {
        rel[0] = rel_h[c * 3 + 0];
        rel[1] = rel_h[c * 3 + 1];
        rel[2] = rel_h[c * 3 + 2];
    } else {
        int cc = c - 128;
        rel[0] = rel_w[cc * 3 + 0];
        rel[1] = rel_w[cc * 3 + 1];
        rel[2] = rel_w[cc * 3 + 2];
    }
    float logit[9], vv[9];
    int idx = 0;
    for (int i = 0; i < 3; ++i) {
        int ih = h + i - 1;
        for (int j = 0; j < 3; ++j) {
            int iw = w + j - 1;
            float kk = 0.f, vvv = 0.f;
            if (ih >= 0 && ih < 64 && iw >= 0 && iw < 64) {
                size_t a = nbase + (size_t)ih * 64 + iw;
                kk = b2f(K[a]);
                vvv = b2f(V[a]);
            }
            float r = use_h ? rel[i] : rel[j];
            logit[idx] = q * (kk + r);
            vv[idx] = vvv;
            ++idx;
        }
    }
    float m = logit[0];
    for (int k = 1; k < 9; ++k) m = fmaxf(m, logit[k]);
    float s = 0.f, o = 0.f;
    for (int k = 0; k < 9; ++k) {
        float e = __expf(logit[k] - m);
        s += e;
        o += e * vv[k];
    }
    out[gid] = o / s;
}

extern "C" void kernel_launch(void* const* d_in, const int* in_sizes, int n_in,
                              void* d_out, int out_size, void* d_ws, size_t ws_size,
                              hipStream_t stream) {
    const float* x = (const float*)d_in[0];
    const float* y = (const float*)d_in[1];
    const float* wq = (const float*)d_in[2];
    const float* wk = (const float*)d_in[3];
    const float* wv = (const float*)d_in[4];
    const float* rel_h = (const float*)d_in[5];
    const float* rel_w = (const float*)d_in[6];
    float* out = (float*)d_out;

    char* ws = (char*)d_ws;
    // workspace layout (bytes):
    //   yT: 0            .. 16777216
    //   xT: 16777216     .. 33554432
    //   wqb/wkb/wvb: 33554432 + {0,131072,262144}
    //   Q:  33947648, K: +16777216, V: +33554432   (total ~84.3 MB)
    unsigned short* yT  = (unsigned short*)(ws);
    unsigned short* xT  = (unsigned short*)(ws + 16777216);
    unsigned short* wqb = (unsigned short*)(ws + 33554432);
    unsigned short* wkb = (unsigned short*)(ws + 33554432 + 131072);
    unsigned short* wvb = (unsigned short*)(ws + 33554432 + 262144);
    unsigned short* Qb  = (unsigned short*)(ws + 33947648);
    unsigned short* Kb  = (unsigned short*)(ws + 33947648 + 16777216);
    unsigned short* Vb  = (unsigned short*)(ws + 33947648 + 33554432);

    transpose_cast<<<dim3(128, 8, 16), 256, 0, stream>>>(y, x, yT, xT);
    wcast<<<256, 256, 0, stream>>>(wq, wk, wv, wqb, wkb, wvb);
    gemm_qkv<<<dim3(256, 2, 3), 256, 0, stream>>>(wqb, wkb, wvb, yT, xT, Qb, Kb, Vb);
    attn<<<32768, 256, 0, stream>>>(Qb, Kb, Vb, rel_h, rel_w, out);
}

// Round 2
// 199.538 us; speedup vs baseline: 1.0914x; 1.0914x over previous
//
#include <hip/hip_runtime.h>
#include <hip/hip_bf16.h>
#include <stdint.h>

typedef __attribute__((ext_vector_type(8))) short short8;
typedef __attribute__((ext_vector_type(4))) float floatx4;
typedef __attribute__((ext_vector_type(4))) unsigned int uintx4;
typedef __attribute__((ext_vector_type(4))) unsigned short ushort4v;

#define HH 64
#define WW 64
#define HWSZ 4096
#define BB 8
#define CIN 256
#define COUT 256
#define NTOT 32768  // B*H*W

__device__ __forceinline__ unsigned short f2b(float f) {
    union { float f; unsigned int u; } v; v.f = f;
    unsigned int r = v.u + 0x7FFFu + ((v.u >> 16) & 1u);
    return (unsigned short)(r >> 16);
}
__device__ __forceinline__ float b2f(unsigned short h) {
    union { unsigned int u; float f; } v; v.u = ((unsigned int)h) << 16;
    return v.f;
}

// ---- transpose + cast: [B][Cin][HW] f32 -> [B*HW][Cin] bf16 ----
__global__ void transpose_cast(const float* __restrict__ y, const float* __restrict__ x,
                               unsigned short* __restrict__ yT, unsigned short* __restrict__ xT) {
    __shared__ float tile[32][33];
    int z = blockIdx.z;          // 0..15: (b, which)
    int which = z & 1;           // 0 -> y, 1 -> x
    int b = z >> 1;
    const float* src = which ? x : y;
    unsigned short* dst = which ? xT : yT;
    int p0 = blockIdx.x * 32;    // pixel tile
    int i0 = blockIdx.y * 32;    // channel tile
    int t = threadIdx.x;
    int p = t & 31;
    int ib = t >> 5;             // 0..7
    const float* sp = src + (size_t)b * CIN * HWSZ + (size_t)i0 * HWSZ + p0;
    for (int r = 0; r < 4; ++r) {
        int i = ib + r * 8;
        tile[i][p] = sp[(size_t)i * HWSZ + p];
    }
    __syncthreads();
    int ii = t & 31;
    int pb = t >> 5;
    unsigned short* dp = dst + ((size_t)b * HWSZ + p0) * CIN + i0;
    for (int r = 0; r < 4; ++r) {
        int pp = pb + r * 8;
        dp[(size_t)pp * CIN + ii] = f2b(tile[ii][pp]);
    }
}

// ---- weight cast: 3x [256][256] f32 -> bf16 (layout unchanged, [m][k]) ----
__global__ void wcast(const float* __restrict__ wq, const float* __restrict__ wk,
                      const float* __restrict__ wv,
                      unsigned short* __restrict__ wqb, unsigned short* __restrict__ wkb,
                      unsigned short* __restrict__ wvb) {
    int idx = blockIdx.x * 256 + threadIdx.x;   // < 65536
    wqb[idx] = f2b(wq[idx]);
    wkb[idx] = f2b(wk[idx]);
    wvb[idx] = f2b(wv[idx]);
}

// ---- GEMM: Out[m][n] = sum_k W[m][k] * InT[n][k], bf16 MFMA 16x16x32 ----
// blockIdx.z selects (W, In, Out) among q/k/v.
#define BM 128
#define BN 128
#define BK 32
#define LDSS 40   // bf16 elems per LDS row (32 + 8 pad) = 80 B, 16B-aligned rows

__global__ __launch_bounds__(256, 4)
void gemm_qkv(const unsigned short* __restrict__ wqb, const unsigned short* __restrict__ wkb,
              const unsigned short* __restrict__ wvb,
              const unsigned short* __restrict__ yT, const unsigned short* __restrict__ xT,
              unsigned short* __restrict__ Qb, unsigned short* __restrict__ Kb,
              unsigned short* __restrict__ Vb) {
    __shared__ unsigned short lA[BM * LDSS];
    __shared__ unsigned short lB[BN * LDSS];

    int z = blockIdx.z;
    const unsigned short* Wb = (z == 0) ? wqb : (z == 1) ? wkb : wvb;
    const unsigned short* In = (z == 0) ? yT : xT;
    unsigned short* Out = (z == 0) ? Qb : (z == 1) ? Kb : Vb;

    int n0 = blockIdx.x * BN;
    int m0 = blockIdx.y * BM;
    int t = threadIdx.x;
    int lane = t & 63;
    int wave = t >> 6;
    int quad = lane >> 4;
    int l16 = lane & 15;
    int wm = (wave >> 1) * 64;
    int wn = (wave & 1) * 64;

    floatx4 acc[4][4];
    for (int mi = 0; mi < 4; ++mi)
        for (int ni = 0; ni < 4; ++ni)
            acc[mi][ni] = (floatx4){0.f, 0.f, 0.f, 0.f};

    int r0 = t >> 2, cch0 = t & 3;          // chunk t
    int r1 = (t + 256) >> 2;                // chunk t+256 (same cch)

    for (int k0 = 0; k0 < CIN; k0 += BK) {
        uintx4 a0 = *(const uintx4*)(Wb + (size_t)(m0 + r0) * CIN + k0 + cch0 * 8);
        uintx4 a1 = *(const uintx4*)(Wb + (size_t)(m0 + r1) * CIN + k0 + cch0 * 8);
        uintx4 b0 = *(const uintx4*)(In + (size_t)(n0 + r0) * CIN + k0 + cch0 * 8);
        uintx4 b1 = *(const uintx4*)(In + (size_t)(n0 + r1) * CIN + k0 + cch0 * 8);
        *(uintx4*)(lA + r0 * LDSS + cch0 * 8) = a0;
        *(uintx4*)(lA + r1 * LDSS + cch0 * 8) = a1;
        *(uintx4*)(lB + r0 * LDSS + cch0 * 8) = b0;
        *(uintx4*)(lB + r1 * LDSS + cch0 * 8) = b1;
        __syncthreads();

        short8 af[4], bf[4];
        for (int mi = 0; mi < 4; ++mi)
            af[mi] = *(const short8*)(lA + (wm + mi * 16 + l16) * LDSS + quad * 8);
        for (int ni = 0; ni < 4; ++ni)
            bf[ni] = *(const short8*)(lB + (wn + ni * 16 + l16) * LDSS + quad * 8);
        for (int mi = 0; mi < 4; ++mi)
            for (int ni = 0; ni < 4; ++ni)
                acc[mi][ni] = __builtin_amdgcn_mfma_f32_16x16x32_bf16(af[mi], bf[ni], acc[mi][ni], 0, 0, 0);
        __syncthreads();
    }

    // epilogue: C/D layout col = lane&15, row = quad*4 + reg
    for (int mi = 0; mi < 4; ++mi) {
        for (int ni = 0; ni < 4; ++ni) {
            int col = n0 + wn + ni * 16 + l16;
            int rowb = m0 + wm + mi * 16 + quad * 4;
            for (int r = 0; r < 4; ++r)
                Out[(size_t)(rowb + r) * NTOT + col] = f2b(acc[mi][ni][r]);
        }
    }
}

// ---- attention v2: each thread computes 4 outputs along W ----
// Q/K/V layout: [C][B][H][W] bf16. out layout: [B][C][H][W] f32.
__global__ __launch_bounds__(256)
void attn(const unsigned short* __restrict__ Q,
          const unsigned short* __restrict__ K,
          const unsigned short* __restrict__ V,
          const float* __restrict__ rel_h,
          const float* __restrict__ rel_w,
          float* __restrict__ out) {
    int gid = blockIdx.x * 256 + threadIdx.x;   // [0, 2097152)
    int w4 = gid & 15;                          // 16 groups of 4 along W
    int w0 = w4 << 2;
    int h = (gid >> 4) & 63;
    int c = (gid >> 10) & 255;
    int b = gid >> 18;

    size_t nb = (size_t)c * NTOT + (size_t)b * HWSZ;   // image base (elements)
    const unsigned short* Kp = K + nb;
    const unsigned short* Vp = V + nb;

    // Q: 4 values
    ushort4v qr = *(const ushort4v*)(Q + nb + h * 64 + w0);
    float q[4] = { b2f(qr.x), b2f(qr.y), b2f(qr.z), b2f(qr.w) };

    // rel: wave-uniform (c uniform within a wave)
    bool use_h = (c < 128);
    float rel3[3];
    if (use_h) {
        rel3[0] = rel_h[c * 3 + 0]; rel3[1] = rel_h[c * 3 + 1]; rel3[2] = rel_h[c * 3 + 2];
    } else {
        int cc = c - 128;
        rel3[0] = rel_w[cc * 3 + 0]; rel3[1] = rel_w[cc * 3 + 1]; rel3[2] = rel_w[cc * 3 + 2];
    }
    float rr[9];
    #pragma unroll
    for (int r = 0; r < 3; ++r)
        #pragma unroll
        for (int j = 0; j < 3; ++j)
            rr[r * 3 + j] = use_h ? rel3[r] : rel3[j];

    // K/V window rows: columns w0-1 .. w0+4 (6 values per row)
    float kb[3][6], vb[3][6];
    #pragma unroll
    for (int r = 0; r < 3; ++r) {
        int ih = h + r - 1;
        bool rok = (unsigned)ih < 64u;
        #pragma unroll
        for (int xx = 0; xx < 6; ++xx) { kb[r][xx] = 0.f; vb[r][xx] = 0.f; }
        if (rok) {
            int ro = ih * 64;
            ushort4v km = *(const ushort4v*)(Kp + ro + w0);
            ushort4v vm = *(const ushort4v*)(Vp + ro + w0);
            kb[r][1] = b2f(km.x); kb[r][2] = b2f(km.y); kb[r][3] = b2f(km.z); kb[r][4] = b2f(km.w);
            vb[r][1] = b2f(vm.x); vb[r][2] = b2f(vm.y); vb[r][3] = b2f(vm.z); vb[r][4] = b2f(vm.w);
            if (w0 > 0)  { kb[r][0] = b2f(Kp[ro + w0 - 1]); vb[r][0] = b2f(Vp[ro + w0 - 1]); }
            if (w0 < 60) { kb[r][5] = b2f(Kp[ro + w0 + 4]); vb[r][5] = b2f(Vp[ro + w0 + 4]); }
        }
    }

    float ov[4];
    #pragma unroll
    for (int wi = 0; wi < 4; ++wi) {
        float qv = q[wi];
        float lg[9];
        #pragma unroll
        for (int r = 0; r < 3; ++r)
            #pragma unroll
            for (int j = 0; j < 3; ++j)
                lg[r * 3 + j] = qv * (kb[r][wi + j] + rr[r * 3 + j]);
        float m = lg[0];
        #pragma unroll
        for (int t = 1; t < 9; ++t) m = fmaxf(m, lg[t]);
        float s = 0.f, o = 0.f;
        #pragma unroll
        for (int r = 0; r < 3; ++r)
            #pragma unroll
            for (int j = 0; j < 3; ++j) {
                float e = __expf(lg[r * 3 + j] - m);
                s += e;
                o += e * vb[r][wi + j];
            }
        ov[wi] = o * __builtin_amdgcn_rcpf(s);
    }

    size_t oi = ((size_t)b * COUT + c) * HWSZ + h * 64 + w0;
    *(floatx4*)(out + oi) = (floatx4){ ov[0], ov[1], ov[2], ov[3] };
}

extern "C" void kernel_launch(void* const* d_in, const int* in_sizes, int n_in,
                              void* d_out, int out_size, void* d_ws, size_t ws_size,
                              hipStream_t stream) {
    const float* x = (const float*)d_in[0];
    const float* y = (const float*)d_in[1];
    const float* wq = (const float*)d_in[2];
    const float* wk = (const float*)d_in[3];
    const float* wv = (const float*)d_in[4];
    const float* rel_h = (const float*)d_in[5];
    const float* rel_w = (const float*)d_in[6];
    float* out = (float*)d_out;

    char* ws = (char*)d_ws;
    unsigned short* yT  = (unsigned short*)(ws);
    unsigned short* xT  = (unsigned short*)(ws + 16777216);
    unsigned short* wqb = (unsigned short*)(ws + 33554432);
    unsigned short* wkb = (unsigned short*)(ws + 33554432 + 131072);
    unsigned short* wvb = (unsigned short*)(ws + 33554432 + 262144);
    unsigned short* Qb  = (unsigned short*)(ws + 33947648);
    unsigned short* Kb  = (unsigned short*)(ws + 33947648 + 16777216);
    unsigned short* Vb  = (unsigned short*)(ws + 33947648 + 33554432);

    transpose_cast<<<dim3(128, 8, 16), 256, 0, stream>>>(y, x, yT, xT);
    wcast<<<256, 256, 0, stream>>>(wq, wk, wv, wqb, wkb, wvb);
    gemm_qkv<<<dim3(256, 2, 3), 256, 0, stream>>>(wqb, wkb, wvb, yT, xT, Qb, Kb, Vb);
    attn<<<8192, 256, 0, stream>>>(Qb, Kb, Vb, rel_h, rel_w, out);
}

// Round 3
// 197.890 us; speedup vs baseline: 1.1005x; 1.0083x over previous
//
#include <hip/hip_runtime.h>
#include <hip/hip_bf16.h>
#include <stdint.h>

typedef __attribute__((ext_vector_type(8))) short short8;
typedef __attribute__((ext_vector_type(4))) float floatx4;
typedef __attribute__((ext_vector_type(4))) unsigned int uintx4;
typedef __attribute__((ext_vector_type(2))) unsigned int uintx2;
typedef __attribute__((ext_vector_type(4))) unsigned short ushort4v;

#define HH 64
#define WW 64
#define HWSZ 4096
#define BB 8
#define CIN 256
#define COUT 256
#define NTOT 32768  // B*H*W

__device__ __forceinline__ unsigned short f2b(float f) {
    union { float f; unsigned int u; } v; v.f = f;
    unsigned int r = v.u + 0x7FFFu + ((v.u >> 16) & 1u);
    return (unsigned short)(r >> 16);
}
__device__ __forceinline__ float b2f(unsigned short h) {
    union { unsigned int u; float f; } v; v.u = ((unsigned int)h) << 16;
    return v.f;
}

// ---- transpose + cast v2: [B][Cin][HW] f32 -> [B*HW][Cin] bf16 ----
// 64x64 tiles, float4 loads, padded LDS (65-dword rows, 2-way max), 16B stores.
__global__ __launch_bounds__(256) void transpose_cast(
        const float* __restrict__ y, const float* __restrict__ x,
        unsigned short* __restrict__ yT, unsigned short* __restrict__ xT) {
    __shared__ float lt[64 * 65];
    int zz = blockIdx.z;         // 0..15: (b, which)
    int which = zz & 1;
    int b = zz >> 1;
    const float* src = which ? x : y;
    unsigned short* dst = which ? xT : yT;
    int p0 = blockIdx.x * 64;    // pixel tile
    int c0 = blockIdx.y * 64;    // channel tile
    int t = threadIdx.x;

    const float* sp = src + ((size_t)b * CIN + c0) * HWSZ + p0;
    int chL = t >> 4;            // 0..15
    int pxL = (t & 15) * 4;      // 0..60
    #pragma unroll
    for (int pass = 0; pass < 4; ++pass) {
        int ch = chL + pass * 16;
        float4 v = *(const float4*)(sp + (size_t)ch * HWSZ + pxL);
        lt[ch * 65 + pxL + 0] = v.x;
        lt[ch * 65 + pxL + 1] = v.y;
        lt[ch * 65 + pxL + 2] = v.z;
        lt[ch * 65 + pxL + 3] = v.w;
    }
    __syncthreads();

    int c8 = (t & 7) * 8;        // channel chunk (8 bf16 = 16 B)
    int pxR = t >> 3;            // 0..31
    unsigned short* dp = dst + ((size_t)b * HWSZ + p0) * CIN + c0 + c8;
    #pragma unroll
    for (int pass = 0; pass < 2; ++pass) {
        int px = pxR + pass * 32;
        unsigned int dw[4];
        #pragma unroll
        for (int j = 0; j < 4; ++j) {
            float lo = lt[(c8 + 2 * j) * 65 + px];
            float hi = lt[(c8 + 2 * j + 1) * 65 + px];
            dw[j] = (unsigned int)f2b(lo) | ((unsigned int)f2b(hi) << 16);
        }
        *(uintx4*)(dp + (size_t)px * CIN) = (uintx4){dw[0], dw[1], dw[2], dw[3]};
    }
}

// ---- weight cast: 3x [256][256] f32 -> bf16 ----
__global__ void wcast(const float* __restrict__ wq, const float* __restrict__ wk,
                      const float* __restrict__ wv,
                      unsigned short* __restrict__ wqb, unsigned short* __restrict__ wkb,
                      unsigned short* __restrict__ wvb) {
    int idx = blockIdx.x * 256 + threadIdx.x;   // < 65536
    wqb[idx] = f2b(wq[idx]);
    wkb[idx] = f2b(wk[idx]);
    wvb[idx] = f2b(wv[idx]);
}

// ---- GEMM v2: LDS-free flat MFMA. Out[m][n] = sum_k W[m][k] * InT[n][k]. ----
// Fragments loaded directly from global (16-B contiguous chunks, full-line use).
// B rows interleaved (n = wn + 4*l16 + ni) so each lane owns 4 consecutive
// output cols -> packed dwordx2 stores, 128 B contiguous per quad-row.
__global__ __launch_bounds__(256)
void gemm_qkv(const unsigned short* __restrict__ wqb, const unsigned short* __restrict__ wkb,
              const unsigned short* __restrict__ wvb,
              const unsigned short* __restrict__ yT, const unsigned short* __restrict__ xT,
              unsigned short* __restrict__ Qb, unsigned short* __restrict__ Kb,
              unsigned short* __restrict__ Vb) {
    int z = blockIdx.z;
    const unsigned short* Wb = (z == 0) ? wqb : (z == 1) ? wkb : wvb;
    const unsigned short* In = (z == 0) ? yT : xT;
    unsigned short* Out = (z == 0) ? Qb : (z == 1) ? Kb : Vb;

    int n0 = blockIdx.x * 128;
    int m0 = blockIdx.y * 128;
    int t = threadIdx.x;
    int lane = t & 63;
    int wave = t >> 6;
    int quad = lane >> 4;
    int l16 = lane & 15;
    int wm = (wave >> 1) * 64;
    int wn = (wave & 1) * 64;

    const unsigned short* Abase = Wb + (size_t)(m0 + wm + l16) * CIN + quad * 8;
    const unsigned short* Bbase = In + (size_t)(n0 + wn + 4 * l16) * CIN + quad * 8;

    floatx4 acc[4][4];
    #pragma unroll
    for (int mi = 0; mi < 4; ++mi)
        #pragma unroll
        for (int ni = 0; ni < 4; ++ni)
            acc[mi][ni] = (floatx4){0.f, 0.f, 0.f, 0.f};

    #pragma unroll 2
    for (int k0 = 0; k0 < CIN; k0 += 32) {
        short8 af[4], bf[4];
        #pragma unroll
        for (int mi = 0; mi < 4; ++mi)
            af[mi] = *(const short8*)(Abase + (size_t)mi * 16 * CIN + k0);
        #pragma unroll
        for (int ni = 0; ni < 4; ++ni)
            bf[ni] = *(const short8*)(Bbase + (size_t)ni * CIN + k0);
        #pragma unroll
        for (int mi = 0; mi < 4; ++mi)
            #pragma unroll
            for (int ni = 0; ni < 4; ++ni)
                acc[mi][ni] = __builtin_amdgcn_mfma_f32_16x16x32_bf16(af[mi], bf[ni], acc[mi][ni], 0, 0, 0);
    }

    // epilogue: lane owns cols n0+wn+4*l16 .. +3 (ni = col offset), rows wm+mi*16+quad*4+r
    int colb = n0 + wn + 4 * l16;
    #pragma unroll
    for (int mi = 0; mi < 4; ++mi) {
        #pragma unroll
        for (int r = 0; r < 4; ++r) {
            int row = m0 + wm + mi * 16 + quad * 4 + r;
            unsigned int lo = (unsigned int)f2b(acc[mi][0][r]) | ((unsigned int)f2b(acc[mi][1][r]) << 16);
            unsigned int hi = (unsigned int)f2b(acc[mi][2][r]) | ((unsigned int)f2b(acc[mi][3][r]) << 16);
            *(uintx2*)(Out + (size_t)row * NTOT + colb) = (uintx2){lo, hi};
        }
    }
}

// ---- attention: each thread computes 4 outputs along W ----
// Q/K/V layout: [C][B][H][W] bf16. out layout: [B][C][H][W] f32.
__global__ __launch_bounds__(256)
void attn(const unsigned short* __restrict__ Q,
          const unsigned short* __restrict__ K,
          const unsigned short* __restrict__ V,
          const float* __restrict__ rel_h,
          const float* __restrict__ rel_w,
          float* __restrict__ out) {
    int gid = blockIdx.x * 256 + threadIdx.x;   // [0, 2097152)
    int w4 = gid & 15;
    int w0 = w4 << 2;
    int h = (gid >> 4) & 63;
    int c = (gid >> 10) & 255;
    int b = gid >> 18;

    size_t nb = (size_t)c * NTOT + (size_t)b * HWSZ;
    const unsigned short* Kp = K + nb;
    const unsigned short* Vp = V + nb;

    ushort4v qr = *(const ushort4v*)(Q + nb + h * 64 + w0);
    float q[4] = { b2f(qr.x), b2f(qr.y), b2f(qr.z), b2f(qr.w) };

    bool use_h = (c < 128);
    float rel3[3];
    if (use_h) {
        rel3[0] = rel_h[c * 3 + 0]; rel3[1] = rel_h[c * 3 + 1]; rel3[2] = rel_h[c * 3 + 2];
    } else {
        int cc = c - 128;
        rel3[0] = rel_w[cc * 3 + 0]; rel3[1] = rel_w[cc * 3 + 1]; rel3[2] = rel_w[cc * 3 + 2];
    }
    float rr[9];
    #pragma unroll
    for (int r = 0; r < 3; ++r)
        #pragma unroll
        for (int j = 0; j < 3; ++j)
            rr[r * 3 + j] = use_h ? rel3[r] : rel3[j];

    float kb[3][6], vb[3][6];
    #pragma unroll
    for (int r = 0; r < 3; ++r) {
        int ih = h + r - 1;
        bool rok = (unsigned)ih < 64u;
        #pragma unroll
        for (int xx = 0; xx < 6; ++xx) { kb[r][xx] = 0.f; vb[r][xx] = 0.f; }
        if (rok) {
            int ro = ih * 64;
            ushort4v km = *(const ushort4v*)(Kp + ro + w0);
            ushort4v vm = *(const ushort4v*)(Vp + ro + w0);
            kb[r][1] = b2f(km.x); kb[r][2] = b2f(km.y); kb[r][3] = b2f(km.z); kb[r][4] = b2f(km.w);
            vb[r][1] = b2f(vm.x); vb[r][2] = b2f(vm.y); vb[r][3] = b2f(vm.z); vb[r][4] = b2f(vm.w);
            if (w0 > 0)  { kb[r][0] = b2f(Kp[ro + w0 - 1]); vb[r][0] = b2f(Vp[ro + w0 - 1]); }
            if (w0 < 60) { kb[r][5] = b2f(Kp[ro + w0 + 4]); vb[r][5] = b2f(Vp[ro + w0 + 4]); }
        }
    }

    float ov[4];
    #pragma unroll
    for (int wi = 0; wi < 4; ++wi) {
        float qv = q[wi];
        float lg[9];
        #pragma unroll
        for (int r = 0; r < 3; ++r)
            #pragma unroll
            for (int j = 0; j < 3; ++j)
                lg[r * 3 + j] = qv * (kb[r][wi + j] + rr[r * 3 + j]);
        float m = lg[0];
        #pragma unroll
        for (int t2 = 1; t2 < 9; ++t2) m = fmaxf(m, lg[t2]);
        float s = 0.f, o = 0.f;
        #pragma unroll
        for (int r = 0; r < 3; ++r)
            #pragma unroll
            for (int j = 0; j < 3; ++j) {
                float e = __expf(lg[r * 3 + j] - m);
                s += e;
                o += e * vb[r][wi + j];
            }
        ov[wi] = o * __builtin_amdgcn_rcpf(s);
    }

    size_t oi = ((size_t)b * COUT + c) * HWSZ + h * 64 + w0;
    *(floatx4*)(out + oi) = (floatx4){ ov[0], ov[1], ov[2], ov[3] };
}

extern "C" void kernel_launch(void* const* d_in, const int* in_sizes, int n_in,
                              void* d_out, int out_size, void* d_ws, size_t ws_size,
                              hipStream_t stream) {
    const float* x = (const float*)d_in[0];
    const float* y = (const float*)d_in[1];
    const float* wq = (const float*)d_in[2];
    const float* wk = (const float*)d_in[3];
    const float* wv = (const float*)d_in[4];
    const float* rel_h = (const float*)d_in[5];
    const float* rel_w = (const float*)d_in[6];
    float* out = (float*)d_out;

    char* ws = (char*)d_ws;
    unsigned short* yT  = (unsigned short*)(ws);
    unsigned short* xT  = (unsigned short*)(ws + 16777216);
    unsigned short* wqb = (unsigned short*)(ws + 33554432);
    unsigned short* wkb = (unsigned short*)(ws + 33554432 + 131072);
    unsigned short* wvb = (unsigned short*)(ws + 33554432 + 262144);
    unsigned short* Qb  = (unsigned short*)(ws + 33947648);
    unsigned short* Kb  = (unsigned short*)(ws + 33947648 + 16777216);
    unsigned short* Vb  = (unsigned short*)(ws + 33947648 + 33554432);

    transpose_cast<<<dim3(64, 4, 16), 256, 0, stream>>>(y, x, yT, xT);
    wcast<<<256, 256, 0, stream>>>(wq, wk, wv, wqb, wkb, wvb);
    gemm_qkv<<<dim3(256, 2, 3), 256, 0, stream>>>(wqb, wkb, wvb, yT, xT, Qb, Kb, Vb);
    attn<<<8192, 256, 0, stream>>>(Qb, Kb, Vb, rel_h, rel_w, out);
}

// Round 4
// 197.063 us; speedup vs baseline: 1.1051x; 1.0042x over previous
//
#include <hip/hip_runtime.h>
#include <hip/hip_bf16.h>
#include <stdint.h>

typedef __attribute__((ext_vector_type(8))) short short8;
typedef __attribute__((ext_vector_type(4))) float floatx4;
typedef __attribute__((ext_vector_type(4))) unsigned int uintx4;
typedef __attribute__((ext_vector_type(2))) unsigned int uintx2;
typedef __attribute__((ext_vector_type(4))) unsigned short ushort4v;

#define HH 64
#define WW 64
#define HWSZ 4096
#define BB 8
#define CIN 256
#define COUT 256
#define NTOT 32768  // B*H*W

__device__ __forceinline__ unsigned short f2b(float f) {
    union { float f; unsigned int u; } v; v.f = f;
    unsigned int r = v.u + 0x7FFFu + ((v.u >> 16) & 1u);
    return (unsigned short)(r >> 16);
}
__device__ __forceinline__ float b2f(unsigned short h) {
    union { unsigned int u; float f; } v; v.u = ((unsigned int)h) << 16;
    return v.f;
}

// ---- transpose + cast: [B][Cin][HW] f32 -> [B*HW][Cin] bf16 ----
__global__ __launch_bounds__(256) void transpose_cast(
        const float* __restrict__ y, const float* __restrict__ x,
        unsigned short* __restrict__ yT, unsigned short* __restrict__ xT) {
    __shared__ float lt[64 * 65];
    int zz = blockIdx.z;         // 0..15: (b, which)
    int which = zz & 1;
    int b = zz >> 1;
    const float* src = which ? x : y;
    unsigned short* dst = which ? xT : yT;
    int p0 = blockIdx.x * 64;    // pixel tile
    int c0 = blockIdx.y * 64;    // channel tile
    int t = threadIdx.x;

    const float* sp = src + ((size_t)b * CIN + c0) * HWSZ + p0;
    int chL = t >> 4;            // 0..15
    int pxL = (t & 15) * 4;      // 0..60
    #pragma unroll
    for (int pass = 0; pass < 4; ++pass) {
        int ch = chL + pass * 16;
        float4 v = *(const float4*)(sp + (size_t)ch * HWSZ + pxL);
        lt[ch * 65 + pxL + 0] = v.x;
        lt[ch * 65 + pxL + 1] = v.y;
        lt[ch * 65 + pxL + 2] = v.z;
        lt[ch * 65 + pxL + 3] = v.w;
    }
    __syncthreads();

    int c8 = (t & 7) * 8;        // channel chunk (8 bf16 = 16 B)
    int pxR = t >> 3;            // 0..31
    unsigned short* dp = dst + ((size_t)b * HWSZ + p0) * CIN + c0 + c8;
    #pragma unroll
    for (int pass = 0; pass < 2; ++pass) {
        int px = pxR + pass * 32;
        unsigned int dw[4];
        #pragma unroll
        for (int j = 0; j < 4; ++j) {
            float lo = lt[(c8 + 2 * j) * 65 + px];
            float hi = lt[(c8 + 2 * j + 1) * 65 + px];
            dw[j] = (unsigned int)f2b(lo) | ((unsigned int)f2b(hi) << 16);
        }
        *(uintx4*)(dp + (size_t)px * CIN) = (uintx4){dw[0], dw[1], dw[2], dw[3]};
    }
}

// ---- weight cast: 3x [256][256] f32 -> bf16 ----
__global__ void wcast(const float* __restrict__ wq, const float* __restrict__ wk,
                      const float* __restrict__ wv,
                      unsigned short* __restrict__ wqb, unsigned short* __restrict__ wkb,
                      unsigned short* __restrict__ wvb) {
    int idx = blockIdx.x * 256 + threadIdx.x;   // < 65536
    wqb[idx] = f2b(wq[idx]);
    wkb[idx] = f2b(wk[idx]);
    wvb[idx] = f2b(wv[idx]);
}

// ---- GEMM v3: LDS-free flat MFMA + explicit register double-buffer ----
// Out[m][n] = sum_k W[m][k] * InT[n][k]. Fragments are 16-B contiguous global
// chunks. K=256 fully unrolled (8 steps); step k+1's 8 fragment loads are
// issued before step k's MFMAs so the compiler emits partial vmcnt waits and
// load latency overlaps compute.
__global__ __launch_bounds__(256)
void gemm_qkv(const unsigned short* __restrict__ wqb, const unsigned short* __restrict__ wkb,
              const unsigned short* __restrict__ wvb,
              const unsigned short* __restrict__ yT, const unsigned short* __restrict__ xT,
              unsigned short* __restrict__ Qb, unsigned short* __restrict__ Kb,
              unsigned short* __restrict__ Vb) {
    int z = blockIdx.z;
    const unsigned short* Wb = (z == 0) ? wqb : (z == 1) ? wkb : wvb;
    const unsigned short* In = (z == 0) ? yT : xT;
    unsigned short* Out = (z == 0) ? Qb : (z == 1) ? Kb : Vb;

    int n0 = blockIdx.x * 128;
    int m0 = blockIdx.y * 128;
    int t = threadIdx.x;
    int lane = t & 63;
    int wave = t >> 6;
    int quad = lane >> 4;
    int l16 = lane & 15;
    int wm = (wave >> 1) * 64;
    int wn = (wave & 1) * 64;

    const unsigned short* Abase = Wb + (size_t)(m0 + wm + l16) * CIN + quad * 8;
    const unsigned short* Bbase = In + (size_t)(n0 + wn + 4 * l16) * CIN + quad * 8;

    floatx4 acc[4][4];
    #pragma unroll
    for (int mi = 0; mi < 4; ++mi)
        #pragma unroll
        for (int ni = 0; ni < 4; ++ni)
            acc[mi][ni] = (floatx4){0.f, 0.f, 0.f, 0.f};

    short8 af[2][4], bf[2][4];
    // prologue: load k-step 0
    #pragma unroll
    for (int mi = 0; mi < 4; ++mi)
        af[0][mi] = *(const short8*)(Abase + (size_t)mi * 16 * CIN);
    #pragma unroll
    for (int ni = 0; ni < 4; ++ni)
        bf[0][ni] = *(const short8*)(Bbase + (size_t)ni * CIN);

    #pragma unroll
    for (int ks = 0; ks < 8; ++ks) {
        int cur = ks & 1;
        int nxt = cur ^ 1;
        if (ks < 7) {
            int k0 = (ks + 1) * 32;
            #pragma unroll
            for (int mi = 0; mi < 4; ++mi)
                af[nxt][mi] = *(const short8*)(Abase + (size_t)mi * 16 * CIN + k0);
            #pragma unroll
            for (int ni = 0; ni < 4; ++ni)
                bf[nxt][ni] = *(const short8*)(Bbase + (size_t)ni * CIN + k0);
        }
        #pragma unroll
        for (int mi = 0; mi < 4; ++mi)
            #pragma unroll
            for (int ni = 0; ni < 4; ++ni)
                acc[mi][ni] = __builtin_amdgcn_mfma_f32_16x16x32_bf16(af[cur][mi], bf[cur][ni], acc[mi][ni], 0, 0, 0);
    }

    // epilogue: lane owns cols n0+wn+4*l16 .. +3, rows wm+mi*16+quad*4+r
    int colb = n0 + wn + 4 * l16;
    #pragma unroll
    for (int mi = 0; mi < 4; ++mi) {
        #pragma unroll
        for (int r = 0; r < 4; ++r) {
            int row = m0 + wm + mi * 16 + quad * 4 + r;
            unsigned int lo = (unsigned int)f2b(acc[mi][0][r]) | ((unsigned int)f2b(acc[mi][1][r]) << 16);
            unsigned int hi = (unsigned int)f2b(acc[mi][2][r]) | ((unsigned int)f2b(acc[mi][3][r]) << 16);
            *(uintx2*)(Out + (size_t)row * NTOT + colb) = (uintx2){lo, hi};
        }
    }
}

// ---- attention v3: each thread computes 8 outputs along W ----
// Q/K/V layout: [C][B][H][W] bf16. out layout: [B][C][H][W] f32.
__global__ __launch_bounds__(256)
void attn(const unsigned short* __restrict__ Q,
          const unsigned short* __restrict__ K,
          const unsigned short* __restrict__ V,
          const float* __restrict__ rel_h,
          const float* __restrict__ rel_w,
          float* __restrict__ out) {
    int gid = blockIdx.x * 256 + threadIdx.x;   // [0, 1048576)
    int w8 = gid & 7;
    int w0 = w8 << 3;
    int h = (gid >> 3) & 63;
    int c = (gid >> 9) & 255;
    int b = gid >> 17;

    size_t nb = (size_t)c * NTOT + (size_t)b * HWSZ;
    const unsigned short* Kp = K + nb;
    const unsigned short* Vp = V + nb;

    short8 qr = *(const short8*)(Q + nb + h * 64 + w0);
    float q[8];
    #pragma unroll
    for (int i = 0; i < 8; ++i) q[i] = b2f((unsigned short)qr[i]);

    bool use_h = (c < 128);
    float rel3[3];
    if (use_h) {
        rel3[0] = rel_h[c * 3 + 0]; rel3[1] = rel_h[c * 3 + 1]; rel3[2] = rel_h[c * 3 + 2];
    } else {
        int cc = c - 128;
        rel3[0] = rel_w[cc * 3 + 0]; rel3[1] = rel_w[cc * 3 + 1]; rel3[2] = rel_w[cc * 3 + 2];
    }
    float rr[9];
    #pragma unroll
    for (int r = 0; r < 3; ++r)
        #pragma unroll
        for (int j = 0; j < 3; ++j)
            rr[r * 3 + j] = use_h ? rel3[r] : rel3[j];

    // K/V window rows: columns w0-1 .. w0+8 (10 values per row)
    float kb[3][10], vb[3][10];
    #pragma unroll
    for (int r = 0; r < 3; ++r) {
        int ih = h + r - 1;
        bool rok = (unsigned)ih < 64u;
        #pragma unroll
        for (int xx = 0; xx < 10; ++xx) { kb[r][xx] = 0.f; vb[r][xx] = 0.f; }
        if (rok) {
            int ro = ih * 64;
            short8 km = *(const short8*)(Kp + ro + w0);
            short8 vm = *(const short8*)(Vp + ro + w0);
            #pragma unroll
            for (int i = 0; i < 8; ++i) {
                kb[r][i + 1] = b2f((unsigned short)km[i]);
                vb[r][i + 1] = b2f((unsigned short)vm[i]);
            }
            if (w0 > 0)  { kb[r][0] = b2f(Kp[ro + w0 - 1]); vb[r][0] = b2f(Vp[ro + w0 - 1]); }
            if (w0 < 56) { kb[r][9] = b2f(Kp[ro + w0 + 8]); vb[r][9] = b2f(Vp[ro + w0 + 8]); }
        }
    }

    float ov[8];
    #pragma unroll
    for (int wi = 0; wi < 8; ++wi) {
        float qv = q[wi];
        float lg[9];
        #pragma unroll
        for (int r = 0; r < 3; ++r)
            #pragma unroll
            for (int j = 0; j < 3; ++j)
                lg[r * 3 + j] = qv * (kb[r][wi + j] + rr[r * 3 + j]);
        float m = lg[0];
        #pragma unroll
        for (int t2 = 1; t2 < 9; ++t2) m = fmaxf(m, lg[t2]);
        float s = 0.f, o = 0.f;
        #pragma unroll
        for (int r = 0; r < 3; ++r)
            #pragma unroll
            for (int j = 0; j < 3; ++j) {
                float e = __expf(lg[r * 3 + j] - m);
                s += e;
                o += e * vb[r][wi + j];
            }
        ov[wi] = o * __builtin_amdgcn_rcpf(s);
    }

    size_t oi = ((size_t)b * COUT + c) * HWSZ + h * 64 + w0;
    *(floatx4*)(out + oi)     = (floatx4){ ov[0], ov[1], ov[2], ov[3] };
    *(floatx4*)(out + oi + 4) = (floatx4){ ov[4], ov[5], ov[6], ov[7] };
}

extern "C" void kernel_launch(void* const* d_in, const int* in_sizes, int n_in,
                              void* d_out, int out_size, void* d_ws, size_t ws_size,
                              hipStream_t stream) {
    const float* x = (const float*)d_in[0];
    const float* y = (const float*)d_in[1];
    const float* wq = (const float*)d_in[2];
    const float* wk = (const float*)d_in[3];
    const float* wv = (const float*)d_in[4];
    const float* rel_h = (const float*)d_in[5];
    const float* rel_w = (const float*)d_in[6];
    float* out = (float*)d_out;

    char* ws = (char*)d_ws;
    unsigned short* yT  = (unsigned short*)(ws);
    unsigned short* xT  = (unsigned short*)(ws + 16777216);
    unsigned short* wqb = (unsigned short*)(ws + 33554432);
    unsigned short* wkb = (unsigned short*)(ws + 33554432 + 131072);
    unsigned short* wvb = (unsigned short*)(ws + 33554432 + 262144);
    unsigned short* Qb  = (unsigned short*)(ws + 33947648);
    unsigned short* Kb  = (unsigned short*)(ws + 33947648 + 16777216);
    unsigned short* Vb  = (unsigned short*)(ws + 33947648 + 33554432);

    transpose_cast<<<dim3(64, 4, 16), 256, 0, stream>>>(y, x, yT, xT);
    wcast<<<256, 256, 0, stream>>>(wq, wk, wv, wqb, wkb, wvb);
    gemm_qkv<<<dim3(256, 2, 3), 256, 0, stream>>>(wqb, wkb, wvb, yT, xT, Qb, Kb, Vb);
    attn<<<4096, 256, 0, stream>>>(Qb, Kb, Vb, rel_h, rel_w, out);
}

// Round 5
// 169.307 us; speedup vs baseline: 1.2863x; 1.1639x over previous
//
#include <hip/hip_runtime.h>
#include <hip/hip_bf16.h>
#include <stdint.h>

typedef __attribute__((ext_vector_type(8))) short short8;
typedef __attribute__((ext_vector_type(4))) float floatx4;
typedef __attribute__((ext_vector_type(4))) unsigned int uintx4;
typedef __attribute__((ext_vector_type(2))) unsigned int uintx2;
typedef __attribute__((ext_vector_type(4))) unsigned short ushort4v;
typedef unsigned int u32;

#define HH 64
#define WW 64
#define HWSZ 4096
#define BB 8
#define CIN 256
#define COUT 256
#define NTOT 32768  // B*H*W

// async global->LDS DMA, 16 B per lane; LDS dest = wave-uniform base + lane*16
#define GLL16(g, l)                                                            \
    __builtin_amdgcn_global_load_lds(                                          \
        (const __attribute__((address_space(1))) u32*)(const void*)(g),        \
        (__attribute__((address_space(3))) u32*)(void*)(l), 16, 0, 0)

__device__ __forceinline__ unsigned short f2b(float f) {
    union { float f; unsigned int u; } v; v.f = f;
    unsigned int r = v.u + 0x7FFFu + ((v.u >> 16) & 1u);
    return (unsigned short)(r >> 16);
}
__device__ __forceinline__ float b2f(unsigned short h) {
    union { unsigned int u; float f; } v; v.u = ((unsigned int)h) << 16;
    return v.f;
}

// ---- transpose + cast: [B][Cin][HW] f32 -> [B*HW][Cin] bf16 ---- (unchanged)
__global__ __launch_bounds__(256) void transpose_cast(
        const float* __restrict__ y, const float* __restrict__ x,
        unsigned short* __restrict__ yT, unsigned short* __restrict__ xT) {
    __shared__ float lt[64 * 65];
    int zz = blockIdx.z;
    int which = zz & 1;
    int b = zz >> 1;
    const float* src = which ? x : y;
    unsigned short* dst = which ? xT : yT;
    int p0 = blockIdx.x * 64;
    int c0 = blockIdx.y * 64;
    int t = threadIdx.x;

    const float* sp = src + ((size_t)b * CIN + c0) * HWSZ + p0;
    int chL = t >> 4;
    int pxL = (t & 15) * 4;
    #pragma unroll
    for (int pass = 0; pass < 4; ++pass) {
        int ch = chL + pass * 16;
        float4 v = *(const float4*)(sp + (size_t)ch * HWSZ + pxL);
        lt[ch * 65 + pxL + 0] = v.x;
        lt[ch * 65 + pxL + 1] = v.y;
        lt[ch * 65 + pxL + 2] = v.z;
        lt[ch * 65 + pxL + 3] = v.w;
    }
    __syncthreads();

    int c8 = (t & 7) * 8;
    int pxR = t >> 3;
    unsigned short* dp = dst + ((size_t)b * HWSZ + p0) * CIN + c0 + c8;
    #pragma unroll
    for (int pass = 0; pass < 2; ++pass) {
        int px = pxR + pass * 32;
        unsigned int dw[4];
        #pragma unroll
        for (int j = 0; j < 4; ++j) {
            float lo = lt[(c8 + 2 * j) * 65 + px];
            float hi = lt[(c8 + 2 * j + 1) * 65 + px];
            dw[j] = (unsigned int)f2b(lo) | ((unsigned int)f2b(hi) << 16);
        }
        *(uintx4*)(dp + (size_t)px * CIN) = (uintx4){dw[0], dw[1], dw[2], dw[3]};
    }
}

// ---- weight cast ---- (unchanged)
__global__ void wcast(const float* __restrict__ wq, const float* __restrict__ wk,
                      const float* __restrict__ wv,
                      unsigned short* __restrict__ wqb, unsigned short* __restrict__ wkb,
                      unsigned short* __restrict__ wvb) {
    int idx = blockIdx.x * 256 + threadIdx.x;
    wqb[idx] = f2b(wq[idx]);
    wkb[idx] = f2b(wk[idx]);
    wvb[idx] = f2b(wv[idx]);
}

// ---- GEMM v4: m97-style global_load_lds staging + MFMA ----
// Out[m][n] = sum_k W[m][k] * InT[n][k].
// LDS A: [m-row 0..127][k 0..31] linear (64 B rows).
// LDS B: n-row r stored at slot (r&3)*32 + (r>>2) so frag reads (n = wn+4*l16+ni)
//        hit stride-64B addresses (2-way banks) AND lane owns 4 consecutive
//        output cols -> packed dwordx2 epilogue stores.
__global__ __launch_bounds__(256)
void gemm_qkv(const unsigned short* __restrict__ wqb, const unsigned short* __restrict__ wkb,
              const unsigned short* __restrict__ wvb,
              const unsigned short* __restrict__ yT, const unsigned short* __restrict__ xT,
              unsigned short* __restrict__ Qb, unsigned short* __restrict__ Kb,
              unsigned short* __restrict__ Vb) {
    __shared__ unsigned short lA[128 * 32];   // 8 KB
    __shared__ unsigned short lB[128 * 32];   // 8 KB

    int z = blockIdx.z;
    const unsigned short* Wb = (z == 0) ? wqb : (z == 1) ? wkb : wvb;
    const unsigned short* In = (z == 0) ? yT : xT;
    unsigned short* Out = (z == 0) ? Qb : (z == 1) ? Kb : Vb;

    int n0 = blockIdx.x * 128;
    int m0 = blockIdx.y * 128;
    int t = threadIdx.x;
    int lane = t & 63;
    int wave = t >> 6;
    int quad = lane >> 4;
    int l16 = lane & 15;
    int wm = (wave >> 1) * 64;
    int wn = (wave & 1) * 64;

    // staging addresses: instr i in {0,1}, this thread covers slot s = i*64 + (t>>2),
    // chunk (t&3)*8 elems within the 32-elem k row.
    int sA0 = t >> 2;                 // A row, i=0 (i=1 adds 64)
    int cch = (t & 3) * 8;
    int sB0 = t >> 2;
    int sB1 = 64 + (t >> 2);
    int gnB0 = 4 * (sB0 & 31) + (sB0 >> 5);   // global n-row for slot sB0
    int gnB1 = 4 * (sB1 & 31) + (sB1 >> 5);

    const unsigned short* gA0 = Wb + (size_t)(m0 + sA0) * CIN + cch;
    const unsigned short* gA1 = Wb + (size_t)(m0 + sA0 + 64) * CIN + cch;
    const unsigned short* gB0 = In + (size_t)(n0 + gnB0) * CIN + cch;
    const unsigned short* gB1 = In + (size_t)(n0 + gnB1) * CIN + cch;

    // wave-uniform LDS dest bases (elems): wave*512 elems (1 KB), instr1 adds 2048 elems
    unsigned short* lA0 = lA + wave * 512;
    unsigned short* lA1 = lA + wave * 512 + 2048;
    unsigned short* lB0 = lB + wave * 512;
    unsigned short* lB1 = lB + wave * 512 + 2048;

    floatx4 acc[4][4];
    #pragma unroll
    for (int mi = 0; mi < 4; ++mi)
        #pragma unroll
        for (int ni = 0; ni < 4; ++ni)
            acc[mi][ni] = (floatx4){0.f, 0.f, 0.f, 0.f};

    // fragment read addresses (constant across k-steps)
    const unsigned short* rdA[4];
    const unsigned short* rdB[4];
    #pragma unroll
    for (int mi = 0; mi < 4; ++mi)
        rdA[mi] = lA + (wm + mi * 16 + l16) * 32 + quad * 8;
    #pragma unroll
    for (int ni = 0; ni < 4; ++ni)
        rdB[ni] = lB + (ni * 32 + (wn >> 2) + l16) * 32 + quad * 8;

    #pragma unroll
    for (int ks = 0; ks < 8; ++ks) {
        int koff = ks * 32;
        GLL16(gA0 + koff, lA0);
        GLL16(gA1 + koff, lA1);
        GLL16(gB0 + koff, lB0);
        GLL16(gB1 + koff, lB1);
        __syncthreads();   // drains vmcnt (incl. global_load_lds) then barrier

        short8 af[4], bf[4];
        #pragma unroll
        for (int mi = 0; mi < 4; ++mi)
            af[mi] = *(const short8*)rdA[mi];
        #pragma unroll
        for (int ni = 0; ni < 4; ++ni)
            bf[ni] = *(const short8*)rdB[ni];
        #pragma unroll
        for (int mi = 0; mi < 4; ++mi)
            #pragma unroll
            for (int ni = 0; ni < 4; ++ni)
                acc[mi][ni] = __builtin_amdgcn_mfma_f32_16x16x32_bf16(af[mi], bf[ni], acc[mi][ni], 0, 0, 0);
        __syncthreads();   // protect LDS before next stage overwrites
    }

    // epilogue: lane owns cols n0+wn+4*l16 .. +3, rows wm+mi*16+quad*4+r
    int colb = n0 + wn + 4 * l16;
    #pragma unroll
    for (int mi = 0; mi < 4; ++mi) {
        #pragma unroll
        for (int r = 0; r < 4; ++r) {
            int row = m0 + wm + mi * 16 + quad * 4 + r;
            unsigned int lo = (unsigned int)f2b(acc[mi][0][r]) | ((unsigned int)f2b(acc[mi][1][r]) << 16);
            unsigned int hi = (unsigned int)f2b(acc[mi][2][r]) | ((unsigned int)f2b(acc[mi][3][r]) << 16);
            *(uintx2*)(Out + (size_t)row * NTOT + colb) = (uintx2){lo, hi};
        }
    }
}

// ---- attention: 8 outputs along W per thread ---- (unchanged)
__global__ __launch_bounds__(256)
void attn(const unsigned short* __restrict__ Q,
          const unsigned short* __restrict__ K,
          const unsigned short* __restrict__ V,
          const float* __restrict__ rel_h,
          const float* __restrict__ rel_w,
          float* __restrict__ out) {
    int gid = blockIdx.x * 256 + threadIdx.x;
    int w8 = gid & 7;
    int w0 = w8 << 3;
    int h = (gid >> 3) & 63;
    int c = (gid >> 9) & 255;
    int b = gid >> 17;

    size_t nb = (size_t)c * NTOT + (size_t)b * HWSZ;
    const unsigned short* Kp = K + nb;
    const unsigned short* Vp = V + nb;

    short8 qr = *(const short8*)(Q + nb + h * 64 + w0);
    float q[8];
    #pragma unroll
    for (int i = 0; i < 8; ++i) q[i] = b2f((unsigned short)qr[i]);

    bool use_h = (c < 128);
    float rel3[3];
    if (use_h) {
        rel3[0] = rel_h[c * 3 + 0]; rel3[1] = rel_h[c * 3 + 1]; rel3[2] = rel_h[c * 3 + 2];
    } else {
        int cc = c - 128;
        rel3[0] = rel_w[cc * 3 + 0]; rel3[1] = rel_w[cc * 3 + 1]; rel3[2] = rel_w[cc * 3 + 2];
    }
    float rr[9];
    #pragma unroll
    for (int r = 0; r < 3; ++r)
        #pragma unroll
        for (int j = 0; j < 3; ++j)
            rr[r * 3 + j] = use_h ? rel3[r] : rel3[j];

    float kb[3][10], vb[3][10];
    #pragma unroll
    for (int r = 0; r < 3; ++r) {
        int ih = h + r - 1;
        bool rok = (unsigned)ih < 64u;
        #pragma unroll
        for (int xx = 0; xx < 10; ++xx) { kb[r][xx] = 0.f; vb[r][xx] = 0.f; }
        if (rok) {
            int ro = ih * 64;
            short8 km = *(const short8*)(Kp + ro + w0);
            short8 vm = *(const short8*)(Vp + ro + w0);
            #pragma unroll
            for (int i = 0; i < 8; ++i) {
                kb[r][i + 1] = b2f((unsigned short)km[i]);
                vb[r][i + 1] = b2f((unsigned short)vm[i]);
            }
            if (w0 > 0)  { kb[r][0] = b2f(Kp[ro + w0 - 1]); vb[r][0] = b2f(Vp[ro + w0 - 1]); }
            if (w0 < 56) { kb[r][9] = b2f(Kp[ro + w0 + 8]); vb[r][9] = b2f(Vp[ro + w0 + 8]); }
        }
    }

    float ov[8];
    #pragma unroll
    for (int wi = 0; wi < 8; ++wi) {
        float qv = q[wi];
        float lg[9];
        #pragma unroll
        for (int r = 0; r < 3; ++r)
            #pragma unroll
            for (int j = 0; j < 3; ++j)
                lg[r * 3 + j] = qv * (kb[r][wi + j] + rr[r * 3 + j]);
        float m = lg[0];
        #pragma unroll
        for (int t2 = 1; t2 < 9; ++t2) m = fmaxf(m, lg[t2]);
        float s = 0.f, o = 0.f;
        #pragma unroll
        for (int r = 0; r < 3; ++r)
            #pragma unroll
            for (int j = 0; j < 3; ++j) {
                float e = __expf(lg[r * 3 + j] - m);
                s += e;
                o += e * vb[r][wi + j];
            }
        ov[wi] = o * __builtin_amdgcn_rcpf(s);
    }

    size_t oi = ((size_t)b * COUT + c) * HWSZ + h * 64 + w0;
    *(floatx4*)(out + oi)     = (floatx4){ ov[0], ov[1], ov[2], ov[3] };
    *(floatx4*)(out + oi + 4) = (floatx4){ ov[4], ov[5], ov[6], ov[7] };
}

extern "C" void kernel_launch(void* const* d_in, const int* in_sizes, int n_in,
                              void* d_out, int out_size, void* d_ws, size_t ws_size,
                              hipStream_t stream) {
    const float* x = (const float*)d_in[0];
    const float* y = (const float*)d_in[1];
    const float* wq = (const float*)d_in[2];
    const float* wk = (const float*)d_in[3];
    const float* wv = (const float*)d_in[4];
    const float* rel_h = (const float*)d_in[5];
    const float* rel_w = (const float*)d_in[6];
    float* out = (float*)d_out;

    char* ws = (char*)d_ws;
    unsigned short* yT  = (unsigned short*)(ws);
    unsigned short* xT  = (unsigned short*)(ws + 16777216);
    unsigned short* wqb = (unsigned short*)(ws + 33554432);
    unsigned short* wkb = (unsigned short*)(ws + 33554432 + 131072);
    unsigned short* wvb = (unsigned short*)(ws + 33554432 + 262144);
    unsigned short* Qb  = (unsigned short*)(ws + 33947648);
    unsigned short* Kb  = (unsigned short*)(ws + 33947648 + 16777216);
    unsigned short* Vb  = (unsigned short*)(ws + 33947648 + 33554432);

    transpose_cast<<<dim3(64, 4, 16), 256, 0, stream>>>(y, x, yT, xT);
    wcast<<<256, 256, 0, stream>>>(wq, wk, wv, wqb, wkb, wvb);
    gemm_qkv<<<dim3(256, 2, 3), 256, 0, stream>>>(wqb, wkb, wvb, yT, xT, Qb, Kb, Vb);
    attn<<<4096, 256, 0, stream>>>(Qb, Kb, Vb, rel_h, rel_w, out);
}

// Round 6
// 159.612 us; speedup vs baseline: 1.3644x; 1.0607x over previous
//
#include <hip/hip_runtime.h>
#include <hip/hip_bf16.h>
#include <stdint.h>

typedef __attribute__((ext_vector_type(8))) short short8;
typedef __attribute__((ext_vector_type(4))) float floatx4;
typedef __attribute__((ext_vector_type(4))) unsigned int uintx4;
typedef __attribute__((ext_vector_type(2))) unsigned int uintx2;
typedef unsigned int u32;

#define HH 64
#define WW 64
#define HWSZ 4096
#define BB 8
#define CIN 256
#define COUT 256
#define NTOT 32768  // B*H*W

// async global->LDS DMA, 16 B per lane; LDS dest = wave-uniform base + lane*16
#define GLL16(g, l)                                                            \
    __builtin_amdgcn_global_load_lds(                                          \
        (const __attribute__((address_space(1))) u32*)(const void*)(g),        \
        (__attribute__((address_space(3))) u32*)(void*)(l), 16, 0, 0)

__device__ __forceinline__ unsigned short f2b(float f) {
    union { float f; unsigned int u; } v; v.f = f;
    unsigned int r = v.u + 0x7FFFu + ((v.u >> 16) & 1u);
    return (unsigned short)(r >> 16);
}
__device__ __forceinline__ float b2f(unsigned short h) {
    union { unsigned int u; float f; } v; v.u = ((unsigned int)h) << 16;
    return v.f;
}

// ---- transpose + cast: [B][Cin][HW] f32 -> [B*HW][Cin] bf16 ---- (unchanged, at BW floor)
__global__ __launch_bounds__(256) void transpose_cast(
        const float* __restrict__ y, const float* __restrict__ x,
        unsigned short* __restrict__ yT, unsigned short* __restrict__ xT) {
    __shared__ float lt[64 * 65];
    int zz = blockIdx.z;
    int which = zz & 1;
    int b = zz >> 1;
    const float* src = which ? x : y;
    unsigned short* dst = which ? xT : yT;
    int p0 = blockIdx.x * 64;
    int c0 = blockIdx.y * 64;
    int t = threadIdx.x;

    const float* sp = src + ((size_t)b * CIN + c0) * HWSZ + p0;
    int chL = t >> 4;
    int pxL = (t & 15) * 4;
    #pragma unroll
    for (int pass = 0; pass < 4; ++pass) {
        int ch = chL + pass * 16;
        float4 v = *(const float4*)(sp + (size_t)ch * HWSZ + pxL);
        lt[ch * 65 + pxL + 0] = v.x;
        lt[ch * 65 + pxL + 1] = v.y;
        lt[ch * 65 + pxL + 2] = v.z;
        lt[ch * 65 + pxL + 3] = v.w;
    }
    __syncthreads();

    int c8 = (t & 7) * 8;
    int pxR = t >> 3;
    unsigned short* dp = dst + ((size_t)b * HWSZ + p0) * CIN + c0 + c8;
    #pragma unroll
    for (int pass = 0; pass < 2; ++pass) {
        int px = pxR + pass * 32;
        unsigned int dw[4];
        #pragma unroll
        for (int j = 0; j < 4; ++j) {
            float lo = lt[(c8 + 2 * j) * 65 + px];
            float hi = lt[(c8 + 2 * j + 1) * 65 + px];
            dw[j] = (unsigned int)f2b(lo) | ((unsigned int)f2b(hi) << 16);
        }
        *(uintx4*)(dp + (size_t)px * CIN) = (uintx4){dw[0], dw[1], dw[2], dw[3]};
    }
}

// ---- weight cast ---- (unchanged)
__global__ void wcast(const float* __restrict__ wq, const float* __restrict__ wk,
                      const float* __restrict__ wv,
                      unsigned short* __restrict__ wqb, unsigned short* __restrict__ wkb,
                      unsigned short* __restrict__ wvb) {
    int idx = blockIdx.x * 256 + threadIdx.x;
    wqb[idx] = f2b(wq[idx]);
    wkb[idx] = f2b(wk[idx]);
    wvb[idx] = f2b(wv[idx]);
}

// ---- GEMM v5: global_load_lds staging, TWO k-chunks per barrier pair ----
// Out[m][n] = sum_k W[m][k] * InT[n][k].
// Per iteration: stage k-chunks 2i and 2i+1 into independent LDS buffers,
// one barrier, 32 MFMAs, one barrier. Keeps the proven 64-B-row / GLL16
// pattern (no padding -> DMA stays contiguous). k accumulation order is
// unchanged -> bitwise-identical output.
__global__ __launch_bounds__(256)
void gemm_qkv(const unsigned short* __restrict__ wqb, const unsigned short* __restrict__ wkb,
              const unsigned short* __restrict__ wvb,
              const unsigned short* __restrict__ yT, const unsigned short* __restrict__ xT,
              unsigned short* __restrict__ Qb, unsigned short* __restrict__ Kb,
              unsigned short* __restrict__ Vb) {
    __shared__ unsigned short lA[2][128 * 32];   // 2 x 8 KB
    __shared__ unsigned short lB[2][128 * 32];   // 2 x 8 KB

    int z = blockIdx.z;
    const unsigned short* Wb = (z == 0) ? wqb : (z == 1) ? wkb : wvb;
    const unsigned short* In = (z == 0) ? yT : xT;
    unsigned short* Out = (z == 0) ? Qb : (z == 1) ? Kb : Vb;

    int n0 = blockIdx.x * 128;
    int m0 = blockIdx.y * 128;
    int t = threadIdx.x;
    int lane = t & 63;
    int wave = t >> 6;
    int quad = lane >> 4;
    int l16 = lane & 15;
    int wm = (wave >> 1) * 64;
    int wn = (wave & 1) * 64;

    // staging: slot s = i*64 + (t>>2), chunk (t&3)*8 elems within 32-elem k row
    int sA0 = t >> 2;
    int cch = (t & 3) * 8;
    int sB0 = t >> 2;
    int sB1 = 64 + (t >> 2);
    int gnB0 = 4 * (sB0 & 31) + (sB0 >> 5);   // B slot permutation: slot = (n&3)*32 + n>>2
    int gnB1 = 4 * (sB1 & 31) + (sB1 >> 5);

    const unsigned short* gA0 = Wb + (size_t)(m0 + sA0) * CIN + cch;
    const unsigned short* gA1 = Wb + (size_t)(m0 + sA0 + 64) * CIN + cch;
    const unsigned short* gB0 = In + (size_t)(n0 + gnB0) * CIN + cch;
    const unsigned short* gB1 = In + (size_t)(n0 + gnB1) * CIN + cch;

    floatx4 acc[4][4];
    #pragma unroll
    for (int mi = 0; mi < 4; ++mi)
        #pragma unroll
        for (int ni = 0; ni < 4; ++ni)
            acc[mi][ni] = (floatx4){0.f, 0.f, 0.f, 0.f};

    #pragma unroll
    for (int it = 0; it < 4; ++it) {
        int k0 = it * 64;            // chunk pair: k0 (buf0), k0+32 (buf1)
        #pragma unroll
        for (int bsel = 0; bsel < 2; ++bsel) {
            int ko = k0 + bsel * 32;
            unsigned short* dA = lA[bsel] + wave * 512;
            unsigned short* dB = lB[bsel] + wave * 512;
            GLL16(gA0 + ko, dA);
            GLL16(gA1 + ko, dA + 2048);
            GLL16(gB0 + ko, dB);
            GLL16(gB1 + ko, dB + 2048);
        }
        __syncthreads();

        #pragma unroll
        for (int bsel = 0; bsel < 2; ++bsel) {
            short8 af[4], bf[4];
            #pragma unroll
            for (int mi = 0; mi < 4; ++mi)
                af[mi] = *(const short8*)(lA[bsel] + (wm + mi * 16 + l16) * 32 + quad * 8);
            #pragma unroll
            for (int ni = 0; ni < 4; ++ni)
                bf[ni] = *(const short8*)(lB[bsel] + (ni * 32 + (wn >> 2) + l16) * 32 + quad * 8);
            #pragma unroll
            for (int mi = 0; mi < 4; ++mi)
                #pragma unroll
                for (int ni = 0; ni < 4; ++ni)
                    acc[mi][ni] = __builtin_amdgcn_mfma_f32_16x16x32_bf16(af[mi], bf[ni], acc[mi][ni], 0, 0, 0);
        }
        __syncthreads();
    }

    // epilogue: lane owns cols n0+wn+4*l16 .. +3, rows wm+mi*16+quad*4+r
    int colb = n0 + wn + 4 * l16;
    #pragma unroll
    for (int mi = 0; mi < 4; ++mi) {
        #pragma unroll
        for (int r = 0; r < 4; ++r) {
            int row = m0 + wm + mi * 16 + quad * 4 + r;
            unsigned int lo = (unsigned int)f2b(acc[mi][0][r]) | ((unsigned int)f2b(acc[mi][1][r]) << 16);
            unsigned int hi = (unsigned int)f2b(acc[mi][2][r]) | ((unsigned int)f2b(acc[mi][3][r]) << 16);
            *(uintx2*)(Out + (size_t)row * NTOT + colb) = (uintx2){lo, hi};
        }
    }
}

// ---- attention v4: 8 outputs/thread, BRANCH-FREE clamped loads + cndmask ----
// Q/K/V layout: [C][B][H][W] bf16. out layout: [B][C][H][W] f32.
// All K/V loads unconditional (clamped addresses, always in-image), zeroed by
// select afterwards -> identical values, but VMEM ops batch into one wait.
__global__ __launch_bounds__(256)
void attn(const unsigned short* __restrict__ Q,
          const unsigned short* __restrict__ K,
          const unsigned short* __restrict__ V,
          const float* __restrict__ rel_h,
          const float* __restrict__ rel_w,
          float* __restrict__ out) {
    int gid = blockIdx.x * 256 + threadIdx.x;
    int w8 = gid & 7;
    int w0 = w8 << 3;
    int h = (gid >> 3) & 63;
    int c = (gid >> 9) & 255;
    int b = gid >> 17;

    size_t nb = (size_t)c * NTOT + (size_t)b * HWSZ;
    const unsigned short* Kp = K + nb;
    const unsigned short* Vp = V + nb;

    short8 qr = *(const short8*)(Q + nb + h * 64 + w0);

    bool use_h = (c < 128);
    float rel3[3];
    if (use_h) {
        rel3[0] = rel_h[c * 3 + 0]; rel3[1] = rel_h[c * 3 + 1]; rel3[2] = rel_h[c * 3 + 2];
    } else {
        int cc = c - 128;
        rel3[0] = rel_w[cc * 3 + 0]; rel3[1] = rel_w[cc * 3 + 1]; rel3[2] = rel_w[cc * 3 + 2];
    }
    float rr[9];
    #pragma unroll
    for (int r = 0; r < 3; ++r)
        #pragma unroll
        for (int j = 0; j < 3; ++j)
            rr[r * 3 + j] = use_h ? rel3[r] : rel3[j];

    int e0 = (w0 > 0) ? w0 - 1 : 0;      // always in-row
    int e9 = (w0 < 56) ? w0 + 8 : 63;
    bool okL = (w0 > 0);
    bool okR = (w0 < 56);

    float kb[3][10], vb[3][10];
    #pragma unroll
    for (int r = 0; r < 3; ++r) {
        int ihr = h + r - 1;
        bool rok = (unsigned)ihr < 64u;
        int ihc = ihr < 0 ? 0 : (ihr > 63 ? 63 : ihr);
        int ro = ihc * 64;
        short8 km = *(const short8*)(Kp + ro + w0);
        short8 vm = *(const short8*)(Vp + ro + w0);
        float ke0 = b2f(Kp[ro + e0]), ve0 = b2f(Vp[ro + e0]);
        float ke9 = b2f(Kp[ro + e9]), ve9 = b2f(Vp[ro + e9]);
        #pragma unroll
        for (int i = 0; i < 8; ++i) {
            kb[r][i + 1] = rok ? b2f((unsigned short)km[i]) : 0.f;
            vb[r][i + 1] = rok ? b2f((unsigned short)vm[i]) : 0.f;
        }
        bool ok0 = rok && okL;
        bool ok9 = rok && okR;
        kb[r][0] = ok0 ? ke0 : 0.f;  vb[r][0] = ok0 ? ve0 : 0.f;
        kb[r][9] = ok9 ? ke9 : 0.f;  vb[r][9] = ok9 ? ve9 : 0.f;
    }

    float q[8];
    #pragma unroll
    for (int i = 0; i < 8; ++i) q[i] = b2f((unsigned short)qr[i]);

    float ov[8];
    #pragma unroll
    for (int wi = 0; wi < 8; ++wi) {
        float qv = q[wi];
        float lg[9];
        #pragma unroll
        for (int r = 0; r < 3; ++r)
            #pragma unroll
            for (int j = 0; j < 3; ++j)
                lg[r * 3 + j] = qv * (kb[r][wi + j] + rr[r * 3 + j]);
        float m = lg[0];
        #pragma unroll
        for (int t2 = 1; t2 < 9; ++t2) m = fmaxf(m, lg[t2]);
        float s = 0.f, o = 0.f;
        #pragma unroll
        for (int r = 0; r < 3; ++r)
            #pragma unroll
            for (int j = 0; j < 3; ++j) {
                float e = __expf(lg[r * 3 + j] - m);
                s += e;
                o += e * vb[r][wi + j];
            }
        ov[wi] = o * __builtin_amdgcn_rcpf(s);
    }

    size_t oi = ((size_t)b * COUT + c) * HWSZ + h * 64 + w0;
    *(floatx4*)(out + oi)     = (floatx4){ ov[0], ov[1], ov[2], ov[3] };
    *(floatx4*)(out + oi + 4) = (floatx4){ ov[4], ov[5], ov[6], ov[7] };
}

extern "C" void kernel_launch(void* const* d_in, const int* in_sizes, int n_in,
                              void* d_out, int out_size, void* d_ws, size_t ws_size,
                              hipStream_t stream) {
    const float* x = (const float*)d_in[0];
    const float* y = (const float*)d_in[1];
    const float* wq = (const float*)d_in[2];
    const float* wk = (const float*)d_in[3];
    const float* wv = (const float*)d_in[4];
    const float* rel_h = (const float*)d_in[5];
    const float* rel_w = (const float*)d_in[6];
    float* out = (float*)d_out;

    char* ws = (char*)d_ws;
    unsigned short* yT  = (unsigned short*)(ws);
    unsigned short* xT  = (unsigned short*)(ws + 16777216);
    unsigned short* wqb = (unsigned short*)(ws + 33554432);
    unsigned short* wkb = (unsigned short*)(ws + 33554432 + 131072);
    unsigned short* wvb = (unsigned short*)(ws + 33554432 + 262144);
    unsigned short* Qb  = (unsigned short*)(ws + 33947648);
    unsigned short* Kb  = (unsigned short*)(ws + 33947648 + 16777216);
    unsigned short* Vb  = (unsigned short*)(ws + 33947648 + 33554432);

    transpose_cast<<<dim3(64, 4, 16), 256, 0, stream>>>(y, x, yT, xT);
    wcast<<<256, 256, 0, stream>>>(wq, wk, wv, wqb, wkb, wvb);
    gemm_qkv<<<dim3(256, 2, 3), 256, 0, stream>>>(wqb, wkb, wvb, yT, xT, Qb, Kb, Vb);
    attn<<<4096, 256, 0, stream>>>(Qb, Kb, Vb, rel_h, rel_w, out);
}